// Round 2
// baseline (56.930 us; speedup 1.0000x reference)
//
#include <hip/hip_runtime.h>

// 54x54-bit array multiplier over {0,1}-valued float bit-vectors.
// The reference's gate network (XOR=a+b-2ab, AND=ab, OR=a+b-ab, ripple-carry
// adders) is EXACT integer binary multiplication on {0,1} inputs, so:
// pack bits -> 64x64->128-bit multiply -> unpack bits. Bit-exact (absmax=0).
//
// One 64-lane wave per batch row:
//   - lane i (i<54) reads A[row][i], B[row][i]  (coalesced scalar loads)
//   - two __ballot()s pack into wave-uniform uint64 a, b (LSB-first)
//   - lo = a*b, hi = __umul64hi(a,b)  => 108-bit product
//   - lanes 0..26 each store one float4 (4 bits -> 4 floats); row stride
//     432 B is 16B-aligned so dwordx4 stores are legal. Lanes 0..15 extract
//     from lo, 16..26 from hi (4*16==64: no lane straddles the boundary).
#define BITS 54
#define OUT_BITS 108

__global__ __launch_bounds__(256) void mult54_kernel(const float* __restrict__ A,
                                                     const float* __restrict__ B,
                                                     float* __restrict__ out,
                                                     int batch) {
    const int gtid = blockIdx.x * blockDim.x + threadIdx.x;
    const int row  = gtid >> 6;          // one wave (64 lanes) per row
    const int lane = threadIdx.x & 63;
    if (row >= batch) return;            // whole waves exit together

    const float* __restrict__ arow = A + (size_t)row * BITS;
    const float* __restrict__ brow = B + (size_t)row * BITS;

    bool abit = false, bbit = false;
    if (lane < BITS) {
        abit = arow[lane] > 0.5f;
        bbit = brow[lane] > 0.5f;
    }
    unsigned long long a = __ballot(abit);   // bit i = lane i's bit (LSB-first)
    unsigned long long b = __ballot(bbit);

    unsigned long long lo = a * b;
    unsigned long long hi = __umul64hi(a, b);   // product bits 64..107 in hi[0..43]

    if (lane < OUT_BITS / 4) {               // 27 lanes store 4 bits each
        unsigned nib = (lane < 16)
            ? (unsigned)((lo >> (4 * lane)) & 0xFull)
            : (unsigned)((hi >> (4 * lane - 64)) & 0xFull);
        float4 v = make_float4((float)(nib & 1u),
                               (float)((nib >> 1) & 1u),
                               (float)((nib >> 2) & 1u),
                               (float)((nib >> 3) & 1u));
        float4* __restrict__ orow4 = (float4*)(out + (size_t)row * OUT_BITS);
        orow4[lane] = v;
    }
}

extern "C" void kernel_launch(void* const* d_in, const int* in_sizes, int n_in,
                              void* d_out, int out_size, void* d_ws, size_t ws_size,
                              hipStream_t stream) {
    const float* A = (const float*)d_in[0];
    const float* B = (const float*)d_in[1];
    float* out = (float*)d_out;

    const int batch = in_sizes[0] / BITS;      // 8192
    const int threads_total = batch * 64;      // one wave per row
    const int block = 256;
    const int grid = (threads_total + block - 1) / block;

    hipLaunchKernelGGL(mult54_kernel, dim3(grid), dim3(block), 0, stream,
                       A, B, out, batch);
}